// Round 7
// baseline (98.277 us; speedup 1.0000x reference)
//
#include <hip/hip_runtime.h>

// AugmentedTripletLoss on MI355X.
// inputs [8192,128] f32, targets [8192] int, center [16,128] f32 -> scalar loss.
//
// v9: BARRIER-FREE pairdist (T3/T4 counted-vmcnt at wave granularity).
// Corrected floor model: MFMA = 12.4 us (25.8 GFLOP @ 2075 TF 16x16 ceiling),
// LDS-read 5.8 us, VALU ~10 us -> composite ~16 us; v2/v4/v8 all stuck at
// ~32-50 us = the 2-barrier-per-stage schedule ceiling (stage+vmcnt(0)+
// barrier dominates, guide m233). Fix: every wave reads the whole B-strip
// anyway, so staging is WAVE-PRIVATE: 3 x 6KB chunk buffers per wave
// (72 KB/block), global_load_lds prefetch 2 chunks ahead, s_waitcnt
// vmcnt(12) (never 0 in the loop), ds-read overwrite guarded by lgkmcnt(0).
// ZERO __syncthreads: 8 independent waves/CU at different phases.
// Kept verified pieces: one-hot +-s class bias in GEMM (K=192, branchless
// epilogue), T21 both-sides XOR swizzle, 64 rows/wave (A=96 VGPR, pinned
// against remat - v5 lesson), T5 setprio, prep fusion, 16-strip slabs.

#define N_ROWS 8192
#define DIM 128
#define KDIM 192          // 128 data dims + 64 one-hot class dims
#define ROWB 384          // KDIM * 2 bytes (bf16)
#define NPROTO 16
#define NSTRIP 16         // 512-col strips
#define NCHUNK 32         // 16-col chunks per strip
#define MARGIN_F 1.0f
#define EPS_F 1e-12f
#define BIAS_F 32768.0f   // 2*s^2 with s=128 (exact in bf16: 0x4300)

typedef __attribute__((ext_vector_type(8))) short short8;   // 8 bf16 = 4 VGPRs
typedef __attribute__((ext_vector_type(4))) float float4v;  // MFMA acc
typedef __attribute__((ext_vector_type(4))) unsigned uint4v;

static __device__ __forceinline__ unsigned f2bf(float f) {
  // round-to-nearest-even bf16 (no NaN expected in this data)
  unsigned u = __float_as_uint(f);
  u += 0x7fffu + ((u >> 16) & 1u);
  return u >> 16;
}

static __device__ __forceinline__ void gload_lds16(const void* g, void* l) {
  __builtin_amdgcn_global_load_lds(
      (const __attribute__((address_space(1))) unsigned*)g,
      (__attribute__((address_space(3))) unsigned*)l, 16, 0, 0);
}

// 512 blocks x 16 rows. Fuses center normalization (redundant per block, 8 KB)
// + row prep: bf16 pack (data + one-hot), ||x||^2, min dist-to-center.
__global__ void prep_kernel(const float* __restrict__ x,
                            const float* __restrict__ center,
                            const int* __restrict__ tgt,
                            char* __restrict__ xbf,
                            float* __restrict__ sq,
                            float* __restrict__ mindc,
                            float* __restrict__ out) {
  __shared__ float scn[NPROTO * DIM];  // normalized prototypes, 8 KB
  int tid = threadIdx.x;
  if (blockIdx.x == 0 && tid == 0) out[0] = 0.0f;  // zero loss accumulator
  int rloc = tid >> 4, l = tid & 15;
  {
    float v[8];
    float ss = 0.f;
#pragma unroll
    for (int j = 0; j < 8; ++j) {
      v[j] = center[rloc * DIM + l * 8 + j];
      ss += v[j] * v[j];
    }
    // 16-lane groups are contiguous in the wave -> masks 1..8 stay in-group
#pragma unroll
    for (int m = 1; m < 16; m <<= 1) ss += __shfl_xor(ss, m, 64);
    float inv = 1.0f / sqrtf(ss);
#pragma unroll
    for (int j = 0; j < 8; ++j) scn[rloc * DIM + l * 8 + j] = v[j] * inv;
  }
  __syncthreads();

  int row = blockIdx.x * 16 + rloc;
  float4 v0 = ((const float4*)x)[row * 32 + l * 2];
  float4 v1 = ((const float4*)x)[row * 32 + l * 2 + 1];
  float ss = v0.x * v0.x + v0.y * v0.y + v0.z * v0.z + v0.w * v0.w +
             v1.x * v1.x + v1.y * v1.y + v1.z * v1.z + v1.w * v1.w;
  float dots[NPROTO];
#pragma unroll
  for (int p = 0; p < NPROTO; ++p) {
    const float* c = &scn[p * DIM + l * 8];
    dots[p] = v0.x * c[0] + v0.y * c[1] + v0.z * c[2] + v0.w * c[3] +
              v1.x * c[4] + v1.y * c[5] + v1.z * c[6] + v1.w * c[7];
  }
#pragma unroll
  for (int m = 1; m < 16; m <<= 1) {
    ss += __shfl_xor(ss, m, 64);
#pragma unroll
    for (int p = 0; p < NPROTO; ++p) dots[p] += __shfl_xor(dots[p], m, 64);
  }
  // data dims: row-major bf16, 384 B/row (first 256 B)
  uint4 pk;
  pk.x = f2bf(v0.x) | (f2bf(v0.y) << 16);
  pk.y = f2bf(v0.z) | (f2bf(v0.w) << 16);
  pk.z = f2bf(v1.x) | (f2bf(v1.y) << 16);
  pk.w = f2bf(v1.z) | (f2bf(v1.w) << 16);
  *(uint4*)(xbf + (size_t)row * ROWB + l * 16) = pk;
  // one-hot class dims (bytes 256..383): -128 (0xC300) at class slot.
  // B side uses the stored -s; A side flips sign in-register -> product -s^2.
  int cls = tgt[row];
  if (l < 8) {
    unsigned wv = (cls & 1) ? 0xC3000000u : 0x0000C300u;  // bf16 -128
    uint4 oh;
    oh.x = ((cls >> 1) == (l * 4 + 0)) ? wv : 0u;
    oh.y = ((cls >> 1) == (l * 4 + 1)) ? wv : 0u;
    oh.z = ((cls >> 1) == (l * 4 + 2)) ? wv : 0u;
    oh.w = ((cls >> 1) == (l * 4 + 3)) ? wv : 0u;
    *(uint4*)(xbf + (size_t)row * ROWB + 256 + l * 16) = oh;
  }
  if (l == 0) {
    float mind2 = INFINITY;
#pragma unroll
    for (int p = 0; p < NPROTO; ++p)
      mind2 = fminf(mind2, ss + 1.0f - 2.0f * dots[p]);  // cn is unit-norm
    sq[row] = ss;
    mindc[row] = fmaxf(sqrtf(fmaxf(mind2, 0.0f)), EPS_F);
  }
}

// Grid: 32 row-groups (256 rows) x 16 strips (512 cols) = 512 blocks
// (= exactly 2 blocks/CU by LDS: 72 KB each). Block = 4 INDEPENDENT waves
// (no barriers anywhere). Wave w owns rows rg*256+w*64..+63 (4 row-tiles)
// and streams the strip in 32 chunks of 16 cols through its private
// triple-buffered LDS region. Prefetch depth 2 via counted vmcnt(12).
// v' = sq_c - 2*dot' tracked; one-hot bias makes positives +32768.
__global__ __launch_bounds__(256, 2) void
pairdist_kernel(const char* __restrict__ xbf, const float* __restrict__ sq,
                float* __restrict__ pmax, float* __restrict__ pmin) {
  __shared__ __align__(16) char bl[4][3 * 6144];  // per-wave 3x(16col x 384B)
  const int wave = threadIdx.x >> 6, lane = threadIdx.x & 63;
  const int q = lane >> 4, l16 = lane & 15;
  const int rg = blockIdx.x >> 4, strip = blockIdx.x & 15;
  const int rowbase = rg * 256 + wave * 64;
  const int stripbase = strip * 512;
  char* const mybuf = bl[wave];

  // T21 staging offsets: LDS dest linear (wave-uniform base + lane*16); the
  // XOR swizzle o' = o ^ ((col&7)<<4) applied to the per-lane GLOBAL source
  // and to the ds_read address (same involution both sides).
  int soff[6];
#pragma unroll
  for (int r = 0; r < 6; ++r) {
    int o = r * 1024 + lane * 16;
    int c = o / ROWB;
    soff[r] = c * ROWB + ((o - c * ROWB) ^ ((c & 7) << 4));
  }
  const char* const srcstrip = xbf + (size_t)stripbase * ROWB;

  auto stage = [&](int ch, int bi) {
    const char* g = srcstrip + (size_t)ch * 6144;  // 16 cols * 384 B
    char* d = mybuf + bi * 6144;
#pragma unroll
    for (int r = 0; r < 6; ++r) gload_lds16(g + soff[r], d + r * 1024);
  };

  // A-frags: A[m=l16][k=q*8+j], 4 row-tiles x 6 k-chunks (last 2 = one-hot,
  // stored -s -> flip sign to +s so the MFMA product is -s^2).
  short8 a[4][6];
#pragma unroll
  for (int rt = 0; rt < 4; ++rt) {
    const char* ar = xbf + (size_t)(rowbase + rt * 16 + l16) * ROWB + q * 16;
#pragma unroll
    for (int kc = 0; kc < 6; ++kc) a[rt][kc] = *(const short8*)(ar + kc * 64);
#pragma unroll
    for (int kc = 4; kc < 6; ++kc) {
      uint4v u = __builtin_bit_cast(uint4v, a[rt][kc]);
      u ^= 0x80008000u;
      a[rt][kc] = __builtin_bit_cast(short8, u);
    }
  }
  // anti-remat pin (v5 lesson): asm is the opaque producer -> no global
  // re-load of fragments inside the chunk loop.
#pragma unroll
  for (int rt = 0; rt < 4; ++rt)
#pragma unroll
    for (int kc = 0; kc < 6; ++kc)
      asm volatile("" : "+v"(a[rt][kc]));

  // Drain all prologue VMEM so steady-state vmcnt counts staging loads only.
  asm volatile("s_waitcnt vmcnt(0)" ::: "memory");
  stage(0, 0);
  stage(1, 1);
  stage(2, 2);

  // Swizzled LDS read offsets (per-lane, chunk-invariant).
  int roffb[6];
#pragma unroll
  for (int kc = 0; kc < 6; ++kc)
    roffb[kc] = (l16 * ROWB + kc * 64 + q * 16) ^ ((l16 & 7) << 4);

  float maxp[16], minn[16];
#pragma unroll
  for (int i = 0; i < 16; ++i) { maxp[i] = -INFINITY; minn[i] = INFINITY; }

  int bi = 0;
#pragma unroll 1
  for (int c = 0; c < NCHUNK; ++c) {
    // Counted wait: chunks c+1, c+2 stay in flight (6 loads each). Tail
    // iterations have fewer outstanding -> tighter counts. Never both
    // buffers drained; extra in-flight loads (sqc below) only make this
    // conservative, never unsafe (waitcnt = "retire until <= N remain").
    if (c < NCHUNK - 2)
      asm volatile("s_waitcnt vmcnt(12)" ::: "memory");
    else if (c == NCHUNK - 2)
      asm volatile("s_waitcnt vmcnt(6)" ::: "memory");
    else
      asm volatile("s_waitcnt vmcnt(0)" ::: "memory");
    float sqc = sq[stripbase + c * 16 + l16];  // issued early, used last
    const char* bufp = mybuf + bi * 6144;
    short8 b[6];
#pragma unroll
    for (int kc = 0; kc < 6; ++kc) b[kc] = *(const short8*)(bufp + roffb[kc]);
    // b in registers before this buffer is overwritten by the prefetch:
    asm volatile("s_waitcnt lgkmcnt(0)" ::: "memory");
    if (c + 3 < NCHUNK) stage(c + 3, bi);  // refill the just-freed buffer
    float4v acc[4];
#pragma unroll
    for (int rt = 0; rt < 4; ++rt) acc[rt] = (float4v){0.f, 0.f, 0.f, 0.f};
    __builtin_amdgcn_s_setprio(1);  // T5: favor the MFMA cluster
#pragma unroll
    for (int kc = 0; kc < 6; ++kc)
#pragma unroll
      for (int rt = 0; rt < 4; ++rt)  // 4 independent acc chains
        acc[rt] = __builtin_amdgcn_mfma_f32_16x16x32_bf16(a[rt][kc], b[kc],
                                                          acc[rt], 0, 0, 0);
    __builtin_amdgcn_s_setprio(0);
    // C/D layout: col = lane&15, row = q*4 + reg (m89-verified).
    // Branchless: positives carry +32768 bias, so max/min need no compare.
#pragma unroll
    for (int rt = 0; rt < 4; ++rt)
#pragma unroll
      for (int r = 0; r < 4; ++r) {
        float v = fmaf(-2.0f, acc[rt][r], sqc);  // dist2 = sq_row + v
        int idx = rt * 4 + r;
        maxp[idx] = fmaxf(maxp[idx], v);
        minn[idx] = fminf(minn[idx], v);
      }
    if (++bi == 3) bi = 0;
  }

  // reduce across the 16 lanes of each quad (xor masks 1..8 stay in-group)
#pragma unroll
  for (int m = 1; m < 16; m <<= 1)
#pragma unroll
    for (int i = 0; i < 16; ++i) {
      maxp[i] = fmaxf(maxp[i], __shfl_xor(maxp[i], m, 64));
      minn[i] = fminf(minn[i], __shfl_xor(minn[i], m, 64));
    }
  // waves own disjoint rows -> no cross-wave reduce; direct scattered store
  if (l16 == 0) {
    float* pM = pmax + (size_t)strip * N_ROWS + rowbase + q * 4;
    float* pm = pmin + (size_t)strip * N_ROWS + rowbase + q * 4;
#pragma unroll
    for (int rt = 0; rt < 4; ++rt)
#pragma unroll
      for (int r = 0; r < 4; ++r) {
        pM[rt * 16 + r] = maxp[rt * 4 + r];
        pm[rt * 16 + r] = minn[rt * 4 + r];
      }
  }
}

__global__ void finalize_kernel(const float* __restrict__ pmax,
                                const float* __restrict__ pmin,
                                const float* __restrict__ sq,
                                const float* __restrict__ mindc,
                                float* __restrict__ out) {
  __shared__ float wsum[4];
  int i = blockIdx.x * 256 + threadIdx.x;  // 32 blocks x 256 = 8192 rows
  float maxv = -INFINITY, minv = INFINITY;
#pragma unroll
  for (int s = 0; s < NSTRIP; ++s) {
    maxv = fmaxf(maxv, pmax[s * N_ROWS + i]);
    minv = fminf(minv, pmin[s * N_ROWS + i]);
  }
  float si = sq[i];
  float dap = sqrtf(fmaxf(si + (maxv - BIAS_F), EPS_F));  // un-bias positives
  // negatives are unbiased (< ~2000); if none exist anywhere, minv is the
  // biased positive min (~32768) -> fall back to dap + margin
  float dan = (minv > 16384.0f) ? (dap + MARGIN_F)
                                : sqrtf(fmaxf(si + minv, EPS_F));
  dan = fminf(dan, mindc[i]);
  float c = fmaxf(dap - dan + MARGIN_F, 0.0f) * (1.0f / (float)N_ROWS);
#pragma unroll
  for (int m = 1; m < 64; m <<= 1) c += __shfl_xor(c, m, 64);
  int lane = threadIdx.x & 63, wv = threadIdx.x >> 6;
  if (lane == 0) wsum[wv] = c;
  __syncthreads();
  if (threadIdx.x == 0) atomicAdd(out, wsum[0] + wsum[1] + wsum[2] + wsum[3]);
}

extern "C" void kernel_launch(void* const* d_in, const int* in_sizes, int n_in,
                              void* d_out, int out_size, void* d_ws, size_t ws_size,
                              hipStream_t stream) {
  const float* inputs = (const float*)d_in[0];
  const int* targets = (const int*)d_in[1];  // per harness: integer -> const int*
  const float* center = (const float*)d_in[2];
  char* ws = (char*)d_ws;
  // ws layout (all 256B-aligned):
  char* xbf    = ws;                       // 8192*384 B bf16+onehot = 3 MB
  float* sq    = (float*)(ws + 3145728);   // 8192 f32 = 32 KB
  float* mindc = (float*)(ws + 3178496);   // 8192 f32 = 32 KB
  float* pmax  = (float*)(ws + 3211264);   // 16*8192 f32 = 512 KB
  float* pmin  = (float*)(ws + 3735552);   // 16*8192 f32 = 512 KB
  float* out   = (float*)d_out;

  prep_kernel<<<512, 256, 0, stream>>>(inputs, center, targets, xbf, sq, mindc, out);
  pairdist_kernel<<<512, 256, 0, stream>>>(xbf, sq, pmax, pmin);
  finalize_kernel<<<32, 256, 0, stream>>>(pmax, pmin, sq, mindc, out);
}